// Round 15
// baseline (98.069 us; speedup 1.0000x reference)
//
#include <hip/hip_runtime.h>
#include <hip/hip_bf16.h>
#include <stdint.h>

typedef unsigned short u16;
typedef float f32x4 __attribute__((ext_vector_type(4)));
typedef float f32x16 __attribute__((ext_vector_type(16)));
typedef short bf16x8 __attribute__((ext_vector_type(8)));

#define NSP 4096      // H*W
#define CDIM 256
#define HID 256
#define NH 8
#define DH 32
#define NG 32
#define CPG 8
#define BATCH 2
#define SPLIT 4       // kv-split (flash-decoding)
#define GN_EPS 1e-5f
// K side carries SCALE^2 * log2(e)  (exp2-domain softmax)
#define QK2_SCALE 0.25503488f

#define MFMA32(A, B, C) __builtin_amdgcn_mfma_f32_32x32x16_bf16(A, B, C, 0, 0, 0)
#define MFMA16(A, B, C) __builtin_amdgcn_mfma_f32_16x16x32_bf16(A, B, C, 0, 0, 0)

__device__ __forceinline__ float bf2f(u16 u) {
    union { uint32_t i; float f; } v; v.i = ((uint32_t)u) << 16; return v.f;
}
__device__ __forceinline__ u16 f2bf(float f) {
    union { float f; uint32_t i; } v; v.f = f;
    uint32_t b = v.i;
    return (u16)((b + 0x7FFFu + ((b >> 16) & 1u)) >> 16);
}

// async global->LDS, 16B per lane; lds must be the wave-uniform base
__device__ __forceinline__ void gload16(const u16* g, u16* lds) {
    __builtin_amdgcn_global_load_lds(
        (const __attribute__((address_space(1))) uint32_t*)g,
        (__attribute__((address_space(3))) uint32_t*)lds, 16, 0, 0);
}

// swap lanes 32-63 of a with lanes 0-31 of b (both updated)
__device__ __forceinline__ void pl32swap(uint32_t& a, uint32_t& b) {
    asm("v_permlane32_swap_b32 %0, %1" : "+v"(a), "+v"(b));
}

// ---------------- GN partial stats (512 blocks) + distributed weight cvt ----------------
__global__ __launch_bounds__(256) void stats_partial(
    const float* __restrict__ x, float* __restrict__ partials,
    const float* __restrict__ wq, const float* __restrict__ wk,
    const float* __restrict__ wv, const float* __restrict__ wout,
    u16* __restrict__ wcat) {
    int blk = blockIdx.x;   // 512 blocks
    int t = threadIdx.x;
#pragma unroll
    for (int i = 0; i < 2; i++) {
        int idx = blk * 512 + i * 256 + t;
        const float* src = (idx < 65536) ? wq : (idx < 131072) ? wk : (idx < 196608) ? wv : wout;
        wcat[idx] = f2bf(src[idx & 65535]);
    }
    int bg = blk >> 3, sl = blk & 7;
    const float4* base = (const float4*)(x + (size_t)bg * (CPG * NSP) + sl * 4096);
    float s = 0.f, ss = 0.f;
#pragma unroll
    for (int i = 0; i < 4; i++) {
        float4 v = base[t + i * 256];
        s  += v.x + v.y + v.z + v.w;
        ss += v.x * v.x + v.y * v.y + v.z * v.z + v.w * v.w;
    }
    for (int m = 1; m < 64; m <<= 1) { s += __shfl_xor(s, m, 64); ss += __shfl_xor(ss, m, 64); }
    __shared__ float ls[4], lss[4];
    int w = t >> 6;
    if ((t & 63) == 0) { ls[w] = s; lss[w] = ss; }
    __syncthreads();
    if (t == 0) {
        partials[bg * 16 + sl * 2]     = ls[0] + ls[1] + ls[2] + ls[3];
        partials[bg * 16 + sl * 2 + 1] = lss[0] + lss[1] + lss[2] + lss[3];
    }
}

// ---------------- GN apply + transpose to (b, n, c) bf16 (finalizes stats inline) ----------------
__global__ void gn_apply(const float* __restrict__ x, const float* __restrict__ partials,
                         const float* __restrict__ gamma, const float* __restrict__ beta,
                         u16* __restrict__ xn) {
    __shared__ u16 tile[64][72];
    __shared__ float mr[8][2];
    int n0 = blockIdx.x * 64, c0 = blockIdx.y * 64, b = blockIdx.z;
    int t = threadIdx.x;
    if (t < 8) {
        int bg = b * NG + (c0 >> 3) + t;
        float s = 0.f, ss = 0.f;
#pragma unroll
        for (int sl = 0; sl < 8; sl++) {
            s  += partials[bg * 16 + sl * 2];
            ss += partials[bg * 16 + sl * 2 + 1];
        }
        float mean = s * (1.0f / 32768.0f);
        float var = ss * (1.0f / 32768.0f) - mean * mean;
        mr[t][0] = mean;
        mr[t][1] = rsqrtf(var + GN_EPS);
    }
    __syncthreads();
    int nl = t & 63, cq = t >> 6;
#pragma unroll
    for (int i = 0; i < 16; i++) {
        int cl = i * 4 + cq;
        int c = c0 + cl;
        float mean = mr[cl >> 3][0];
        float rstd = mr[cl >> 3][1];
        float v = x[((size_t)b * CDIM + c) * NSP + n0 + nl];
        v = (v - mean) * rstd * gamma[c] + beta[c];
        tile[cl][nl] = f2bf(v);
    }
    __syncthreads();
    int nr = t >> 2, cc = (t & 3) * 16;
    uint4 o0, o1;
    u16* p0 = (u16*)&o0; u16* p1 = (u16*)&o1;
#pragma unroll
    for (int j = 0; j < 8; j++) { p0[j] = tile[cc + j][nr]; p1[j] = tile[cc + 8 + j][nr]; }
    size_t orow = ((size_t)b * NSP + n0 + nr) * CDIM + c0 + cc;
    *(uint4*)(xn + orow) = o0;
    *(uint4*)(xn + orow + 8) = o1;
}

// ---------------- fused q/k/v projection, 128x128 tile, vectorized LDS-transposed epilogue ----------------
__global__ __launch_bounds__(256) void gemm_qkv(
    const u16* __restrict__ A, const u16* __restrict__ wcat,
    const float* __restrict__ bq, const float* __restrict__ bk, const float* __restrict__ bv,
    u16* __restrict__ qb, u16* __restrict__ kfb, u16* __restrict__ vfb) {
    __shared__ u16 SMEM[128 * 136];   // 34.8KB: staging (As|Bs 32KB) then epilogue tile
    u16* As = SMEM;
    u16* Bs = SMEM + 8192;
    int bz = blockIdx.z;
    const u16* Ab = A + (size_t)bz * NSP * CDIM;
    int n0 = blockIdx.x * 128, m0 = blockIdx.y * 128;
    int seg = n0 >> 8;                 // 0=q 1=k 2=v
    int t = threadIdx.x, lane = t & 63, w = t >> 6;
    int wr = w >> 1, wc = w & 1;
    f32x4 acc[4][4] = {};

    int srow = w * 8 + (lane >> 3);
    int scol = (lane & 7) * 8;
    const u16* asrc = Ab + (size_t)(m0 + srow) * CDIM + scol;
    const u16* bsrc = wcat + (size_t)(n0 + srow) * CDIM + scol;
    u16* albase = As + w * 512;
    u16* blbase = Bs + w * 512;

    int frow = lane & 15, fcol = (lane >> 4) * 8;

    for (int k0 = 0; k0 < CDIM; k0 += 64) {
        __syncthreads();
#pragma unroll
        for (int ro = 0; ro < 4; ro++) {
            gload16(asrc + (size_t)ro * 32 * CDIM + k0, albase + ro * 2048);
            gload16(bsrc + (size_t)ro * 32 * CDIM + k0, blbase + ro * 2048);
        }
        asm volatile("s_waitcnt vmcnt(0)" ::: "memory");
        __syncthreads();
#pragma unroll
        for (int kk = 0; kk < 2; kk++) {
            bf16x8 af[4], bfv[4];
#pragma unroll
            for (int i = 0; i < 4; i++) {
                af[i]  = *(bf16x8*)&As[(wr * 64 + i * 16 + frow) * 64 + kk * 32 + fcol];
                bfv[i] = *(bf16x8*)&Bs[(wc * 64 + i * 16 + frow) * 64 + kk * 32 + fcol];
            }
#pragma unroll
            for (int i = 0; i < 4; i++)
#pragma unroll
                for (int j = 0; j < 4; j++)
                    acc[i][j] = MFMA16(af[i], bfv[j], acc[i][j]);
        }
    }

    const float* bias = (seg == 0) ? bq : (seg == 1) ? bk : bv;
    int r4 = (lane >> 4) * 4, cx = lane & 15;
    const int STR = 136;
    __syncthreads();   // all waves done reading As/Bs before SMEM reuse

    if (seg <= 1) {
#pragma unroll
        for (int i = 0; i < 4; i++) {
            int row_l = wr * 64 + i * 16 + r4;
#pragma unroll
            for (int j = 0; j < 4; j++) {
                int col_l = wc * 64 + j * 16 + cx;
                float bb = bias[(n0 & 255) + col_l];
#pragma unroll
                for (int r = 0; r < 4; r++) {
                    float vv = acc[i][j][r] + bb;
                    if (seg == 1) vv *= QK2_SCALE;
                    SMEM[(row_l + r) * STR + col_l] = f2bf(vv);
                }
            }
        }
        __syncthreads();
        if (seg == 0) {
#pragma unroll
            for (int i = 0; i < 8; i++) {
                int c = i * 256 + t;
                int row = c >> 4, o = c & 15;
                uint4 v = *(uint4*)&SMEM[row * STR + o * 8];
                *(uint4*)(qb + (size_t)bz * NSP * HID + (size_t)(m0 + row) * HID + (n0 & 255) + o * 8) = v;
            }
        } else {
#pragma unroll
            for (int i = 0; i < 8; i++) {
                int c = i * 256 + t;
                int rl = c & 127, o = c >> 7;
                int colg = (n0 & 255) + o * 8;
                int h2 = colg >> 5;
                int rg = m0 + rl;
                int f = 2 * ((rg >> 5) & 1) + ((colg >> 4) & 1);
                size_t off = ((size_t)(bz * NH + h2) * 64 + (rg >> 6)) * 2048 + (size_t)f * 512
                           + (size_t)(rg & 31) * 8 + (size_t)((colg >> 3) & 1) * 256;
                *(uint4*)(kfb + off) = *(uint4*)&SMEM[rl * STR + o * 8];
            }
        }
    } else {
#pragma unroll
        for (int i = 0; i < 4; i++) {
            int row_l = wr * 64 + i * 16 + r4;
#pragma unroll
            for (int j = 0; j < 4; j++) {
                int col_l = wc * 64 + j * 16 + cx;
                float bb = bias[(n0 & 255) + col_l];
                uint2 pk2;
                pk2.x = ((uint32_t)f2bf(acc[i][j][1] + bb) << 16) | f2bf(acc[i][j][0] + bb);
                pk2.y = ((uint32_t)f2bf(acc[i][j][3] + bb) << 16) | f2bf(acc[i][j][2] + bb);
                *(uint2*)&SMEM[col_l * STR + row_l] = pk2;
            }
        }
        __syncthreads();
#pragma unroll
        for (int i = 0; i < 8; i++) {
            int c = i * 256 + t;
            int dl = c & 127, jl = c >> 7;
            int colg = (n0 & 255) + dl;
            int h2 = colg >> 5, d = colg & 31;
            int ng = m0 + jl * 8;
            int jc = (ng >> 3) & 7;
            size_t off = ((size_t)(bz * NH + h2) * 64 + (ng >> 6)) * 2048 + (size_t)(jc >> 1) * 512
                       + (size_t)(d + (jc & 1) * 32) * 8;
            *(uint4*)(vfb + off) = *(uint4*)&SMEM[dl * STR + jl * 8];
        }
    }
}

// ---------------- final GEMM: out = wout * ao^T + bout + x, 128x128 tile (m97 structure) ----------------
// A = wout bf16 (256x256, rows o, cols c); B = ao (b, n, 256); out f32 (b, o, n); resid = x
__global__ __launch_bounds__(256) void gemm_out(
    const u16* __restrict__ A,
    const u16* __restrict__ B, long sB,
    const float* __restrict__ bias,
    const float* __restrict__ resid, long sR,
    float* __restrict__ outp, long sO) {
    __shared__ u16 As[128 * 64];
    __shared__ u16 Bs[128 * 64];
    int bz = blockIdx.z;
    const u16* Bb = B + (size_t)bz * sB;
    int n0 = blockIdx.x * 128, m0 = blockIdx.y * 128;
    int t = threadIdx.x, lane = t & 63, w = t >> 6;
    int wr = w >> 1, wc = w & 1;
    f32x4 acc[4][4] = {};

    int srow = w * 8 + (lane >> 3);
    int scol = (lane & 7) * 8;
    const u16* asrc = A + (size_t)(m0 + srow) * CDIM + scol;
    const u16* bsrc = Bb + (size_t)(n0 + srow) * CDIM + scol;
    u16* albase = As + w * 512;
    u16* blbase = Bs + w * 512;

    int frow = lane & 15, fcol = (lane >> 4) * 8;

    for (int k0 = 0; k0 < CDIM; k0 += 64) {
        __syncthreads();
#pragma unroll
        for (int ro = 0; ro < 4; ro++) {
            gload16(asrc + (size_t)ro * 32 * CDIM + k0, albase + ro * 2048);
            gload16(bsrc + (size_t)ro * 32 * CDIM + k0, blbase + ro * 2048);
        }
        asm volatile("s_waitcnt vmcnt(0)" ::: "memory");
        __syncthreads();
#pragma unroll
        for (int kk = 0; kk < 2; kk++) {
            bf16x8 af[4], bfv[4];
#pragma unroll
            for (int i = 0; i < 4; i++) {
                af[i]  = *(bf16x8*)&As[(wr * 64 + i * 16 + frow) * 64 + kk * 32 + fcol];
                bfv[i] = *(bf16x8*)&Bs[(wc * 64 + i * 16 + frow) * 64 + kk * 32 + fcol];
            }
#pragma unroll
            for (int i = 0; i < 4; i++)
#pragma unroll
                for (int j = 0; j < 4; j++)
                    acc[i][j] = MFMA16(af[i], bfv[j], acc[i][j]);
        }
    }

    int r4 = (lane >> 4) * 4, cx = lane & 15;
#pragma unroll
    for (int i = 0; i < 4; i++) {
        int rbase = m0 + wr * 64 + i * 16 + r4;   // output channel o
#pragma unroll
        for (int j = 0; j < 4; j++) {
            int col = n0 + wc * 64 + j * 16 + cx; // spatial n
#pragma unroll
            for (int r = 0; r < 4; r++) {
                int row = rbase + r;
                outp[(size_t)bz * sO + (size_t)row * NSP + col] =
                    acc[i][j][r] + bias[row] + resid[(size_t)bz * sR + (size_t)row * NSP + col];
            }
        }
    }
}

// ---------------- flash attention: barrier-free, LDS-free, DUAL q-stream, 2-tile prefetch ----------------
__global__ __launch_bounds__(256, 3) void attn_kernel(
    const u16* __restrict__ q, const u16* __restrict__ kfb,
    const u16* __restrict__ vfb, u16* __restrict__ po, float* __restrict__ zz) {
    __shared__ float Ls[4][64];
    int h = blockIdx.y;
    int bz = blockIdx.z;
    int b = bz / SPLIT, sp = bz % SPLIT;
    int kv0 = sp * (NSP / SPLIT);
    int t = threadIdx.x, lane = t & 63, w = t >> 6;
    int ql = lane & 31, hi = lane >> 5;
    int q0 = blockIdx.x * 256 + w * 64;   // stream a: q0..q0+31, stream b: q0+32..q0+63

    const u16* qbp = q + (size_t)b * NSP * HID + (size_t)(q0 + ql) * HID + h * DH + hi * 8;
    bf16x8 qa0 = *(const bf16x8*)(qbp);
    bf16x8 qa1 = *(const bf16x8*)(qbp + 16);
    bf16x8 qb0 = *(const bf16x8*)(qbp + 32 * HID);
    bf16x8 qb1 = *(const bf16x8*)(qbp + 32 * HID + 16);

    size_t tbase = ((size_t)(b * NH + h) * 64 + (kv0 >> 6)) * 2048 + (size_t)lane * 8;
    const u16* kp = kfb + tbase;
    const u16* vp = vfb + tbase;

#define LOADKF(kd, it) { \
    kd[0] = *(const bf16x8*)(kp + (size_t)(it) * 2048);        \
    kd[1] = *(const bf16x8*)(kp + (size_t)(it) * 2048 + 512);  \
    kd[2] = *(const bf16x8*)(kp + (size_t)(it) * 2048 + 1024); \
    kd[3] = *(const bf16x8*)(kp + (size_t)(it) * 2048 + 1536); }
#define LOADVF(vd, it) { \
    vd[0] = *(const bf16x8*)(vp + (size_t)(it) * 2048);        \
    vd[1] = *(const bf16x8*)(vp + (size_t)(it) * 2048 + 512);  \
    vd[2] = *(const bf16x8*)(vp + (size_t)(it) * 2048 + 1024); \
    vd[3] = *(const bf16x8*)(vp + (size_t)(it) * 2048 + 1536); }

    f32x16 kzero = {};
    f32x16 oacc_a = {}, oacc_b = {};
    float la0 = 0.f, la1 = 0.f, lb0 = 0.f, lb1 = 0.f;

    auto softpv = [&](f32x16& st, const bf16x8 (&vf)[4], int tt, f32x16& oacc,
                      float& l0, float& l1) {
        uint32_t pk[8];
#pragma unroll
        for (int j = 0; j < 8; j++) {
            float p0 = __builtin_amdgcn_exp2f(st[2 * j]);
            float p1 = __builtin_amdgcn_exp2f(st[2 * j + 1]);
            float ps = p0 + p1;
            if (j & 1) l1 += ps; else l0 += ps;
            uint32_t dd;
            asm("v_cvt_pk_bf16_f32 %0, %1, %2" : "=v"(dd) : "v"(p0), "v"(p1));
            pk[j] = dd;
        }
#pragma unroll
        for (int c = 0; c < 2; c++) {
            uint32_t a0 = pk[4 * c + 0], b0 = pk[4 * c + 2];
            uint32_t a1 = pk[4 * c + 1], b1 = pk[4 * c + 3];
            pl32swap(a0, b0);
            pl32swap(a1, b1);
            union { uint32_t u[4]; bf16x8 v8; } fr;
            fr.u[0] = a0; fr.u[1] = a1; fr.u[2] = b0; fr.u[3] = b1;
            __builtin_amdgcn_s_setprio(1);
            oacc = MFMA32(fr.v8, vf[2 * tt + c], oacc);
            __builtin_amdgcn_s_setprio(0);
        }
    };

    auto process = [&](const bf16x8 (&kf)[4], const bf16x8 (&vf)[4]) {
#pragma unroll
        for (int tt = 0; tt < 2; tt++) {
            __builtin_amdgcn_s_setprio(1);
            f32x16 st_a = MFMA32(kf[2 * tt], qa0, kzero);
            st_a = MFMA32(kf[2 * tt + 1], qa1, st_a);
            f32x16 st_b = MFMA32(kf[2 * tt], qb0, kzero);
            st_b = MFMA32(kf[2 * tt + 1], qb1, st_b);
            __builtin_amdgcn_s_setprio(0);
            softpv(st_a, vf, tt, oacc_a, la0, la1);
            softpv(st_b, vf, tt, oacc_b, lb0, lb1);
        }
    };

    const int NT = (NSP / SPLIT) / 64;   // 16 tiles (even)
    bf16x8 k0[4], v0[4], k1[4], v1[4];
    LOADKF(k0, 0); LOADVF(v0, 0);
    LOADKF(k1, 1); LOADVF(v1, 1);
    for (int it = 0; it < NT; it += 2) {
        process(k0, v0);
        int n2 = (it + 2 < NT) ? it + 2 : 0;
        LOADKF(k0, n2); LOADVF(v0, n2);
        process(k1, v1);
        int n3 = (it + 3 < NT) ? it + 3 : 0;
        LOADKF(k1, n3); LOADVF(v1, n3);
    }
#undef LOADKF
#undef LOADVF

    float la = la0 + la1;
    float lb = lb0 + lb1;
    la += __shfl_xor(la, 32);
    lb += __shfl_xor(lb, 32);
    Ls[w][ql] = 1.0f / la;
    Ls[w][32 + ql] = 1.0f / lb;
    if (hi == 0) {
        zz[(((size_t)bz * NH + h) * NSP) + q0 + ql] = __log2f(la);
        zz[(((size_t)bz * NH + h) * NSP) + q0 + 32 + ql] = __log2f(lb);
    }
    u16* pob = po + ((((size_t)bz * NH + h) * NSP) + q0) * DH + ql;
#pragma unroll
    for (int r = 0; r < 16; r++) {
        int qq = (r & 3) + 8 * (r >> 2) + 4 * hi;
        pob[(size_t)qq * DH] = f2bf(oacc_a[r] * Ls[w][qq]);
        pob[(size_t)(32 + qq) * DH] = f2bf(oacc_b[r] * Ls[w][32 + qq]);
    }
}

// ---------------- combine splits -> ao (b,n,hid) bf16 ----------------
__global__ __launch_bounds__(256) void combine_kernel(
    const u16* __restrict__ po, const float* __restrict__ zz, u16* __restrict__ ao) {
    int idx = blockIdx.x * 256 + threadIdx.x;       // B*NSP*HID/8 threads
    int c8 = idx & 31;
    int n  = (idx >> 5) & (NSP - 1);
    int b  = idx >> 17;
    int h  = c8 >> 2;
    int dp = (c8 & 3) * 8;

    float z[SPLIT];
    size_t base[SPLIT];
    float M = -3e38f;
#pragma unroll
    for (int s = 0; s < SPLIT; s++) {
        base[s] = ((((size_t)(b * SPLIT + s) * NH + h) * NSP) + n);
        z[s] = zz[base[s]];
        M = fmaxf(M, z[s]);
    }
    float wsum = 0.f, acc[8] = {};
#pragma unroll
    for (int s = 0; s < SPLIT; s++) {
        float ww = __builtin_amdgcn_exp2f(z[s] - M);
        wsum += ww;
        uint4 o = *(const uint4*)(po + base[s] * DH + dp);
        const u16* op = (const u16*)&o;
#pragma unroll
        for (int j = 0; j < 8; j++) acc[j] += bf2f(op[j]) * ww;
    }
    float inv = 1.0f / wsum;
    uint4 r;
    u16* rp = (u16*)&r;
#pragma unroll
    for (int j = 0; j < 8; j++) rp[j] = f2bf(acc[j] * inv);
    *(uint4*)(ao + (((size_t)b * NSP + n) * HID) + h * DH + dp) = r;
}

extern "C" void kernel_launch(void* const* d_in, const int* in_sizes, int n_in,
                              void* d_out, int out_size, void* d_ws, size_t ws_size,
                              hipStream_t stream) {
    const float* x     = (const float*)d_in[0];
    const float* gamma = (const float*)d_in[1];
    const float* beta  = (const float*)d_in[2];
    const float* wq    = (const float*)d_in[3];
    const float* bq    = (const float*)d_in[4];
    const float* wk    = (const float*)d_in[5];
    const float* bk    = (const float*)d_in[6];
    const float* wv    = (const float*)d_in[7];
    const float* bv    = (const float*)d_in[8];
    const float* wout  = (const float*)d_in[9];
    const float* bout  = (const float*)d_in[10];
    float* out = (float*)d_out;

    char* ws = (char*)d_ws;
    float* partials = (float*)ws;                    // 64*8*2 floats = 4KB
    u16* wq_b = (u16*)(ws + 4096);                   // wq|wk|wv|wout contiguous
    u16* wo_b = wq_b + 3 * 65536;
    u16* xn = wo_b + 65536;                          // (b,n,c) bf16, 4 MB
    u16* qb = xn + (size_t)BATCH * NSP * CDIM;       // (b,n,hid) 4 MB
    u16* kfb = qb + (size_t)BATCH * NSP * HID;       // frag K 4 MB
    u16* vfb = kfb + (size_t)BATCH * NH * 64 * 2048; // frag V 4 MB
    u16* aob = vfb + (size_t)BATCH * NH * 64 * 2048; // (b,n,hid) 4 MB
    u16* pob = aob + (size_t)BATCH * NSP * HID;      // (b,sp,h,n,d) 16 MB
    float* zzb = (float*)(pob + (size_t)SPLIT * BATCH * NH * NSP * DH);  // 1 MB

    const long sQ = (long)NSP * HID;
    const long sOut = (long)CDIM * NSP;

    stats_partial<<<512, 256, 0, stream>>>(x, partials, wq, wk, wv, wout, wq_b);
    gn_apply<<<dim3(NSP / 64, CDIM / 64, BATCH), 256, 0, stream>>>(x, partials, gamma, beta, xn);

    gemm_qkv<<<dim3(768 / 128, NSP / 128, BATCH), 256, 0, stream>>>(
        xn, wq_b, bq, bk, bv, qb, kfb, vfb);

    attn_kernel<<<dim3(NSP / 256, NH, BATCH * SPLIT), 256, 0, stream>>>(qb, kfb, vfb, pob, zzb);
    combine_kernel<<<(BATCH * NSP * HID / 8) / 256, 256, 0, stream>>>(pob, zzb, aob);

    gemm_out<<<dim3(NSP / 128, CDIM / 128, BATCH), 256, 0, stream>>>(
        wo_b, aob, sQ, bout, x, sOut, out, sOut);
}

// Round 16
// 82.142 us; speedup vs baseline: 1.1939x; 1.1939x over previous
//
#include <hip/hip_runtime.h>
#include <hip/hip_bf16.h>
#include <stdint.h>

typedef unsigned short u16;
typedef float f32x4 __attribute__((ext_vector_type(4)));
typedef float f32x16 __attribute__((ext_vector_type(16)));
typedef short bf16x8 __attribute__((ext_vector_type(8)));

#define NSP 4096      // H*W
#define CDIM 256
#define HID 256
#define NH 8
#define DH 32
#define NG 32
#define CPG 8
#define BATCH 2
#define SPLIT 4       // kv-split (flash-decoding)
#define GN_EPS 1e-5f
// K side carries SCALE^2 * log2(e)  (exp2-domain softmax)
#define QK2_SCALE 0.25503488f

#define MFMA32(A, B, C) __builtin_amdgcn_mfma_f32_32x32x16_bf16(A, B, C, 0, 0, 0)
#define MFMA16(A, B, C) __builtin_amdgcn_mfma_f32_16x16x32_bf16(A, B, C, 0, 0, 0)

__device__ __forceinline__ float bf2f(u16 u) {
    union { uint32_t i; float f; } v; v.i = ((uint32_t)u) << 16; return v.f;
}
__device__ __forceinline__ u16 f2bf(float f) {
    union { float f; uint32_t i; } v; v.f = f;
    uint32_t b = v.i;
    return (u16)((b + 0x7FFFu + ((b >> 16) & 1u)) >> 16);
}

// async global->LDS, 16B per lane; lds must be the wave-uniform base
__device__ __forceinline__ void gload16(const u16* g, u16* lds) {
    __builtin_amdgcn_global_load_lds(
        (const __attribute__((address_space(1))) uint32_t*)g,
        (__attribute__((address_space(3))) uint32_t*)lds, 16, 0, 0);
}

// swap lanes 32-63 of a with lanes 0-31 of b (both updated)
__device__ __forceinline__ void pl32swap(uint32_t& a, uint32_t& b) {
    asm("v_permlane32_swap_b32 %0, %1" : "+v"(a), "+v"(b));
}

// ---------------- GN partial stats (512 blocks) + distributed weight cvt ----------------
__global__ __launch_bounds__(256) void stats_partial(
    const float* __restrict__ x, float* __restrict__ partials,
    const float* __restrict__ wq, const float* __restrict__ wk,
    const float* __restrict__ wv, const float* __restrict__ wout,
    u16* __restrict__ wcat) {
    int blk = blockIdx.x;   // 512 blocks
    int t = threadIdx.x;
#pragma unroll
    for (int i = 0; i < 2; i++) {
        int idx = blk * 512 + i * 256 + t;
        const float* src = (idx < 65536) ? wq : (idx < 131072) ? wk : (idx < 196608) ? wv : wout;
        wcat[idx] = f2bf(src[idx & 65535]);
    }
    int bg = blk >> 3, sl = blk & 7;
    const float4* base = (const float4*)(x + (size_t)bg * (CPG * NSP) + sl * 4096);
    float s = 0.f, ss = 0.f;
#pragma unroll
    for (int i = 0; i < 4; i++) {
        float4 v = base[t + i * 256];
        s  += v.x + v.y + v.z + v.w;
        ss += v.x * v.x + v.y * v.y + v.z * v.z + v.w * v.w;
    }
    for (int m = 1; m < 64; m <<= 1) { s += __shfl_xor(s, m, 64); ss += __shfl_xor(ss, m, 64); }
    __shared__ float ls[4], lss[4];
    int w = t >> 6;
    if ((t & 63) == 0) { ls[w] = s; lss[w] = ss; }
    __syncthreads();
    if (t == 0) {
        partials[bg * 16 + sl * 2]     = ls[0] + ls[1] + ls[2] + ls[3];
        partials[bg * 16 + sl * 2 + 1] = lss[0] + lss[1] + lss[2] + lss[3];
    }
}

// ---------------- GN apply + transpose to (b, n, c) bf16 (finalizes stats inline) ----------------
__global__ void gn_apply(const float* __restrict__ x, const float* __restrict__ partials,
                         const float* __restrict__ gamma, const float* __restrict__ beta,
                         u16* __restrict__ xn) {
    __shared__ u16 tile[64][72];
    __shared__ float mr[8][2];
    int n0 = blockIdx.x * 64, c0 = blockIdx.y * 64, b = blockIdx.z;
    int t = threadIdx.x;
    if (t < 8) {
        int bg = b * NG + (c0 >> 3) + t;
        float s = 0.f, ss = 0.f;
#pragma unroll
        for (int sl = 0; sl < 8; sl++) {
            s  += partials[bg * 16 + sl * 2];
            ss += partials[bg * 16 + sl * 2 + 1];
        }
        float mean = s * (1.0f / 32768.0f);
        float var = ss * (1.0f / 32768.0f) - mean * mean;
        mr[t][0] = mean;
        mr[t][1] = rsqrtf(var + GN_EPS);
    }
    __syncthreads();
    int nl = t & 63, cq = t >> 6;
#pragma unroll
    for (int i = 0; i < 16; i++) {
        int cl = i * 4 + cq;
        int c = c0 + cl;
        float mean = mr[cl >> 3][0];
        float rstd = mr[cl >> 3][1];
        float v = x[((size_t)b * CDIM + c) * NSP + n0 + nl];
        v = (v - mean) * rstd * gamma[c] + beta[c];
        tile[cl][nl] = f2bf(v);
    }
    __syncthreads();
    int nr = t >> 2, cc = (t & 3) * 16;
    uint4 o0, o1;
    u16* p0 = (u16*)&o0; u16* p1 = (u16*)&o1;
#pragma unroll
    for (int j = 0; j < 8; j++) { p0[j] = tile[cc + j][nr]; p1[j] = tile[cc + 8 + j][nr]; }
    size_t orow = ((size_t)b * NSP + n0 + nr) * CDIM + c0 + cc;
    *(uint4*)(xn + orow) = o0;
    *(uint4*)(xn + orow + 8) = o1;
}

// ---------------- fused q/k/v projection, 128x128 tile, vectorized LDS-transposed epilogue ----------------
__global__ __launch_bounds__(256) void gemm_qkv(
    const u16* __restrict__ A, const u16* __restrict__ wcat,
    const float* __restrict__ bq, const float* __restrict__ bk, const float* __restrict__ bv,
    u16* __restrict__ qb, u16* __restrict__ kfb, u16* __restrict__ vfb) {
    __shared__ u16 SMEM[128 * 136];   // 34.8KB: staging (As|Bs 32KB) then epilogue tile
    u16* As = SMEM;
    u16* Bs = SMEM + 8192;
    int bz = blockIdx.z;
    const u16* Ab = A + (size_t)bz * NSP * CDIM;
    int n0 = blockIdx.x * 128, m0 = blockIdx.y * 128;
    int seg = n0 >> 8;                 // 0=q 1=k 2=v
    int t = threadIdx.x, lane = t & 63, w = t >> 6;
    int wr = w >> 1, wc = w & 1;
    f32x4 acc[4][4] = {};

    int srow = w * 8 + (lane >> 3);
    int scol = (lane & 7) * 8;
    const u16* asrc = Ab + (size_t)(m0 + srow) * CDIM + scol;
    const u16* bsrc = wcat + (size_t)(n0 + srow) * CDIM + scol;
    u16* albase = As + w * 512;
    u16* blbase = Bs + w * 512;

    int frow = lane & 15, fcol = (lane >> 4) * 8;

    for (int k0 = 0; k0 < CDIM; k0 += 64) {
        __syncthreads();
#pragma unroll
        for (int ro = 0; ro < 4; ro++) {
            gload16(asrc + (size_t)ro * 32 * CDIM + k0, albase + ro * 2048);
            gload16(bsrc + (size_t)ro * 32 * CDIM + k0, blbase + ro * 2048);
        }
        asm volatile("s_waitcnt vmcnt(0)" ::: "memory");
        __syncthreads();
#pragma unroll
        for (int kk = 0; kk < 2; kk++) {
            bf16x8 af[4], bfv[4];
#pragma unroll
            for (int i = 0; i < 4; i++) {
                af[i]  = *(bf16x8*)&As[(wr * 64 + i * 16 + frow) * 64 + kk * 32 + fcol];
                bfv[i] = *(bf16x8*)&Bs[(wc * 64 + i * 16 + frow) * 64 + kk * 32 + fcol];
            }
#pragma unroll
            for (int i = 0; i < 4; i++)
#pragma unroll
                for (int j = 0; j < 4; j++)
                    acc[i][j] = MFMA16(af[i], bfv[j], acc[i][j]);
        }
    }

    const float* bias = (seg == 0) ? bq : (seg == 1) ? bk : bv;
    int r4 = (lane >> 4) * 4, cx = lane & 15;
    const int STR = 136;
    __syncthreads();   // all waves done reading As/Bs before SMEM reuse

    if (seg <= 1) {
#pragma unroll
        for (int i = 0; i < 4; i++) {
            int row_l = wr * 64 + i * 16 + r4;
#pragma unroll
            for (int j = 0; j < 4; j++) {
                int col_l = wc * 64 + j * 16 + cx;
                float bb = bias[(n0 & 255) + col_l];
#pragma unroll
                for (int r = 0; r < 4; r++) {
                    float vv = acc[i][j][r] + bb;
                    if (seg == 1) vv *= QK2_SCALE;
                    SMEM[(row_l + r) * STR + col_l] = f2bf(vv);
                }
            }
        }
        __syncthreads();
        if (seg == 0) {
#pragma unroll
            for (int i = 0; i < 8; i++) {
                int c = i * 256 + t;
                int row = c >> 4, o = c & 15;
                uint4 v = *(uint4*)&SMEM[row * STR + o * 8];
                *(uint4*)(qb + (size_t)bz * NSP * HID + (size_t)(m0 + row) * HID + (n0 & 255) + o * 8) = v;
            }
        } else {
#pragma unroll
            for (int i = 0; i < 8; i++) {
                int c = i * 256 + t;
                int rl = c & 127, o = c >> 7;
                int colg = (n0 & 255) + o * 8;
                int h2 = colg >> 5;
                int rg = m0 + rl;
                int f = 2 * ((rg >> 5) & 1) + ((colg >> 4) & 1);
                size_t off = ((size_t)(bz * NH + h2) * 64 + (rg >> 6)) * 2048 + (size_t)f * 512
                           + (size_t)(rg & 31) * 8 + (size_t)((colg >> 3) & 1) * 256;
                *(uint4*)(kfb + off) = *(uint4*)&SMEM[rl * STR + o * 8];
            }
        }
    } else {
#pragma unroll
        for (int i = 0; i < 4; i++) {
            int row_l = wr * 64 + i * 16 + r4;
#pragma unroll
            for (int j = 0; j < 4; j++) {
                int col_l = wc * 64 + j * 16 + cx;
                float bb = bias[(n0 & 255) + col_l];
                uint2 pk2;
                pk2.x = ((uint32_t)f2bf(acc[i][j][1] + bb) << 16) | f2bf(acc[i][j][0] + bb);
                pk2.y = ((uint32_t)f2bf(acc[i][j][3] + bb) << 16) | f2bf(acc[i][j][2] + bb);
                *(uint2*)&SMEM[col_l * STR + row_l] = pk2;
            }
        }
        __syncthreads();
#pragma unroll
        for (int i = 0; i < 8; i++) {
            int c = i * 256 + t;
            int dl = c & 127, jl = c >> 7;
            int colg = (n0 & 255) + dl;
            int h2 = colg >> 5, d = colg & 31;
            int ng = m0 + jl * 8;
            int jc = (ng >> 3) & 7;
            size_t off = ((size_t)(bz * NH + h2) * 64 + (ng >> 6)) * 2048 + (size_t)(jc >> 1) * 512
                       + (size_t)(d + (jc & 1) * 32) * 8;
            *(uint4*)(vfb + off) = *(uint4*)&SMEM[dl * STR + jl * 8];
        }
    }
}

// ---------------- final GEMM + fused split-combine ----------------
// out[b,o,n] = wout(o,:) . combine(po,zz)[b,n,:] + bout[o] + x[b,o,n]
// 64x64 tile (round-14 structure, 512 blocks); B-tile staged by combining the 4 kv-splits
// in-register (exactly combine_kernel's math) before the LDS write.
__global__ __launch_bounds__(256) void gemm_out(
    const u16* __restrict__ A,           // wout bf16 (256x256)
    const u16* __restrict__ po, const float* __restrict__ zz,
    const float* __restrict__ bias,
    const float* __restrict__ resid, long sR,
    float* __restrict__ outp, long sO,
    int N) {
    __shared__ u16 As[64][72];
    __shared__ u16 Bs[64][72];
    int bz = blockIdx.z;
    int m0 = blockIdx.y * 64, n0 = blockIdx.x * 64;
    int t = threadIdx.x, lane = t & 63, w = t >> 6;
    int wm = (w >> 1) * 32, wn = (w & 1) * 32;
    f32x4 acc[2][2] = {};

    int sr = t >> 2;
    int sc1 = (t & 3) * 8, sc2 = sc1 + 32;
    int nrow = n0 + sr;
    const size_t SSTRIDE = (size_t)NH * NSP;   // split stride in zz rows

    // combined B value for channels [c, c+8) of spatial row nrow
    auto cmb = [&](int c) -> uint4 {
        int h = c >> 5, d = c & 31;
        size_t zb = (((size_t)(bz * SPLIT) * NH + h) * NSP) + nrow;
        float z0 = zz[zb];
        float z1 = zz[zb + SSTRIDE];
        float z2 = zz[zb + 2 * SSTRIDE];
        float z3 = zz[zb + 3 * SSTRIDE];
        float M = fmaxf(fmaxf(z0, z1), fmaxf(z2, z3));
        float w0 = __builtin_amdgcn_exp2f(z0 - M);
        float w1 = __builtin_amdgcn_exp2f(z1 - M);
        float w2 = __builtin_amdgcn_exp2f(z2 - M);
        float w3 = __builtin_amdgcn_exp2f(z3 - M);
        float inv = 1.0f / (w0 + w1 + w2 + w3);
        uint4 o0 = *(const uint4*)(po + zb * DH + d);
        uint4 o1 = *(const uint4*)(po + (zb + SSTRIDE) * DH + d);
        uint4 o2 = *(const uint4*)(po + (zb + 2 * SSTRIDE) * DH + d);
        uint4 o3 = *(const uint4*)(po + (zb + 3 * SSTRIDE) * DH + d);
        const u16* p0 = (const u16*)&o0;
        const u16* p1 = (const u16*)&o1;
        const u16* p2 = (const u16*)&o2;
        const u16* p3 = (const u16*)&o3;
        uint4 r;
        u16* rp = (u16*)&r;
#pragma unroll
        for (int j = 0; j < 8; j++) {
            float a = (bf2f(p0[j]) * w0 + bf2f(p1[j]) * w1 + bf2f(p2[j]) * w2 + bf2f(p3[j]) * w3) * inv;
            rp[j] = f2bf(a);
        }
        return r;
    };

    uint4 av0 = *(const uint4*)(A + (size_t)(m0 + sr) * CDIM + sc1);
    uint4 av1 = *(const uint4*)(A + (size_t)(m0 + sr) * CDIM + sc2);

    for (int k0 = 0; k0 < CDIM; k0 += 64) {
        uint4 bv0 = cmb(k0 + sc1);
        uint4 bv1 = cmb(k0 + sc2);
        __syncthreads();
        *(uint4*)&As[sr][sc1] = av0;
        *(uint4*)&As[sr][sc2] = av1;
        *(uint4*)&Bs[sr][sc1] = bv0;
        *(uint4*)&Bs[sr][sc2] = bv1;
        __syncthreads();
        if (k0 + 64 < CDIM) {
            av0 = *(const uint4*)(A + (size_t)(m0 + sr) * CDIM + k0 + 64 + sc1);
            av1 = *(const uint4*)(A + (size_t)(m0 + sr) * CDIM + k0 + 64 + sc2);
        }
#pragma unroll
        for (int ks = 0; ks < 2; ks++) {
            bf16x8 af[2], bfr[2];
#pragma unroll
            for (int i = 0; i < 2; i++) {
                af[i]  = *(bf16x8*)&As[wm + i * 16 + (lane & 15)][ks * 32 + (lane >> 4) * 8];
                bfr[i] = *(bf16x8*)&Bs[wn + i * 16 + (lane & 15)][ks * 32 + (lane >> 4) * 8];
            }
#pragma unroll
            for (int i = 0; i < 2; i++)
#pragma unroll
                for (int j = 0; j < 2; j++)
                    acc[i][j] = MFMA16(af[i], bfr[j], acc[i][j]);
        }
    }

    int r4 = (lane >> 4) * 4, cx = lane & 15;
#pragma unroll
    for (int i = 0; i < 2; i++)
#pragma unroll
        for (int j = 0; j < 2; j++) {
            int rbase = m0 + wm + i * 16 + r4;
            int cbase = n0 + wn + j * 16 + cx;
#pragma unroll
            for (int r = 0; r < 4; r++) {
                int row = rbase + r, col = cbase;
                outp[(size_t)bz * sO + (size_t)row * N + col] =
                    acc[i][j][r] + bias[row] + resid[(size_t)bz * sR + (size_t)row * N + col];
            }
        }
}

// ---------------- flash attention: barrier-free, LDS-free, DUAL q-stream, 2-tile prefetch ----------------
__global__ __launch_bounds__(256, 3) void attn_kernel(
    const u16* __restrict__ q, const u16* __restrict__ kfb,
    const u16* __restrict__ vfb, u16* __restrict__ po, float* __restrict__ zz) {
    __shared__ float Ls[4][64];
    int h = blockIdx.y;
    int bz = blockIdx.z;
    int b = bz / SPLIT, sp = bz % SPLIT;
    int kv0 = sp * (NSP / SPLIT);
    int t = threadIdx.x, lane = t & 63, w = t >> 6;
    int ql = lane & 31, hi = lane >> 5;
    int q0 = blockIdx.x * 256 + w * 64;   // stream a: q0..q0+31, stream b: q0+32..q0+63

    const u16* qbp = q + (size_t)b * NSP * HID + (size_t)(q0 + ql) * HID + h * DH + hi * 8;
    bf16x8 qa0 = *(const bf16x8*)(qbp);
    bf16x8 qa1 = *(const bf16x8*)(qbp + 16);
    bf16x8 qb0 = *(const bf16x8*)(qbp + 32 * HID);
    bf16x8 qb1 = *(const bf16x8*)(qbp + 32 * HID + 16);

    size_t tbase = ((size_t)(b * NH + h) * 64 + (kv0 >> 6)) * 2048 + (size_t)lane * 8;
    const u16* kp = kfb + tbase;
    const u16* vp = vfb + tbase;

#define LOADKF(kd, it) { \
    kd[0] = *(const bf16x8*)(kp + (size_t)(it) * 2048);        \
    kd[1] = *(const bf16x8*)(kp + (size_t)(it) * 2048 + 512);  \
    kd[2] = *(const bf16x8*)(kp + (size_t)(it) * 2048 + 1024); \
    kd[3] = *(const bf16x8*)(kp + (size_t)(it) * 2048 + 1536); }
#define LOADVF(vd, it) { \
    vd[0] = *(const bf16x8*)(vp + (size_t)(it) * 2048);        \
    vd[1] = *(const bf16x8*)(vp + (size_t)(it) * 2048 + 512);  \
    vd[2] = *(const bf16x8*)(vp + (size_t)(it) * 2048 + 1024); \
    vd[3] = *(const bf16x8*)(vp + (size_t)(it) * 2048 + 1536); }

    f32x16 kzero = {};
    f32x16 oacc_a = {}, oacc_b = {};
    float la0 = 0.f, la1 = 0.f, lb0 = 0.f, lb1 = 0.f;

    auto softpv = [&](f32x16& st, const bf16x8 (&vf)[4], int tt, f32x16& oacc,
                      float& l0, float& l1) {
        uint32_t pk[8];
#pragma unroll
        for (int j = 0; j < 8; j++) {
            float p0 = __builtin_amdgcn_exp2f(st[2 * j]);
            float p1 = __builtin_amdgcn_exp2f(st[2 * j + 1]);
            float ps = p0 + p1;
            if (j & 1) l1 += ps; else l0 += ps;
            uint32_t dd;
            asm("v_cvt_pk_bf16_f32 %0, %1, %2" : "=v"(dd) : "v"(p0), "v"(p1));
            pk[j] = dd;
        }
#pragma unroll
        for (int c = 0; c < 2; c++) {
            uint32_t a0 = pk[4 * c + 0], b0 = pk[4 * c + 2];
            uint32_t a1 = pk[4 * c + 1], b1 = pk[4 * c + 3];
            pl32swap(a0, b0);
            pl32swap(a1, b1);
            union { uint32_t u[4]; bf16x8 v8; } fr;
            fr.u[0] = a0; fr.u[1] = a1; fr.u[2] = b0; fr.u[3] = b1;
            __builtin_amdgcn_s_setprio(1);
            oacc = MFMA32(fr.v8, vf[2 * tt + c], oacc);
            __builtin_amdgcn_s_setprio(0);
        }
    };

    auto process = [&](const bf16x8 (&kf)[4], const bf16x8 (&vf)[4]) {
#pragma unroll
        for (int tt = 0; tt < 2; tt++) {
            __builtin_amdgcn_s_setprio(1);
            f32x16 st_a = MFMA32(kf[2 * tt], qa0, kzero);
            st_a = MFMA32(kf[2 * tt + 1], qa1, st_a);
            f32x16 st_b = MFMA32(kf[2 * tt], qb0, kzero);
            st_b = MFMA32(kf[2 * tt + 1], qb1, st_b);
            __builtin_amdgcn_s_setprio(0);
            softpv(st_a, vf, tt, oacc_a, la0, la1);
            softpv(st_b, vf, tt, oacc_b, lb0, lb1);
        }
    };

    const int NT = (NSP / SPLIT) / 64;   // 16 tiles (even)
    bf16x8 k0[4], v0[4], k1[4], v1[4];
    LOADKF(k0, 0); LOADVF(v0, 0);
    LOADKF(k1, 1); LOADVF(v1, 1);
    for (int it = 0; it < NT; it += 2) {
        process(k0, v0);
        int n2 = (it + 2 < NT) ? it + 2 : 0;
        LOADKF(k0, n2); LOADVF(v0, n2);
        process(k1, v1);
        int n3 = (it + 3 < NT) ? it + 3 : 0;
        LOADKF(k1, n3); LOADVF(v1, n3);
    }
#undef LOADKF
#undef LOADVF

    float la = la0 + la1;
    float lb = lb0 + lb1;
    la += __shfl_xor(la, 32);
    lb += __shfl_xor(lb, 32);
    Ls[w][ql] = 1.0f / la;
    Ls[w][32 + ql] = 1.0f / lb;
    if (hi == 0) {
        zz[(((size_t)bz * NH + h) * NSP) + q0 + ql] = __log2f(la);
        zz[(((size_t)bz * NH + h) * NSP) + q0 + 32 + ql] = __log2f(lb);
    }
    u16* pob = po + ((((size_t)bz * NH + h) * NSP) + q0) * DH + ql;
#pragma unroll
    for (int r = 0; r < 16; r++) {
        int qq = (r & 3) + 8 * (r >> 2) + 4 * hi;
        pob[(size_t)qq * DH] = f2bf(oacc_a[r] * Ls[w][qq]);
        pob[(size_t)(32 + qq) * DH] = f2bf(oacc_b[r] * Ls[w][32 + qq]);
    }
}

extern "C" void kernel_launch(void* const* d_in, const int* in_sizes, int n_in,
                              void* d_out, int out_size, void* d_ws, size_t ws_size,
                              hipStream_t stream) {
    const float* x     = (const float*)d_in[0];
    const float* gamma = (const float*)d_in[1];
    const float* beta  = (const float*)d_in[2];
    const float* wq    = (const float*)d_in[3];
    const float* bq    = (const float*)d_in[4];
    const float* wk    = (const float*)d_in[5];
    const float* bk    = (const float*)d_in[6];
    const float* wv    = (const float*)d_in[7];
    const float* bv    = (const float*)d_in[8];
    const float* wout  = (const float*)d_in[9];
    const float* bout  = (const float*)d_in[10];
    float* out = (float*)d_out;

    char* ws = (char*)d_ws;
    float* partials = (float*)ws;                    // 64*8*2 floats = 4KB
    u16* wq_b = (u16*)(ws + 4096);                   // wq|wk|wv|wout contiguous
    u16* wo_b = wq_b + 3 * 65536;
    u16* xn = wo_b + 65536;                          // (b,n,c) bf16, 4 MB
    u16* qb = xn + (size_t)BATCH * NSP * CDIM;       // (b,n,hid) 4 MB
    u16* kfb = qb + (size_t)BATCH * NSP * HID;       // frag K 4 MB
    u16* vfb = kfb + (size_t)BATCH * NH * 64 * 2048; // frag V 4 MB
    u16* aob = vfb + (size_t)BATCH * NH * 64 * 2048; // (unused, kept for layout)
    u16* pob = aob + (size_t)BATCH * NSP * HID;      // (b,sp,h,n,d) 16 MB
    float* zzb = (float*)(pob + (size_t)SPLIT * BATCH * NH * NSP * DH);  // 1 MB

    const long sOut = (long)CDIM * NSP;

    stats_partial<<<512, 256, 0, stream>>>(x, partials, wq, wk, wv, wout, wq_b);
    gn_apply<<<dim3(NSP / 64, CDIM / 64, BATCH), 256, 0, stream>>>(x, partials, gamma, beta, xn);

    gemm_qkv<<<dim3(768 / 128, NSP / 128, BATCH), 256, 0, stream>>>(
        xn, wq_b, bq, bk, bv, qb, kfb, vfb);

    attn_kernel<<<dim3(NSP / 256, NH, BATCH * SPLIT), 256, 0, stream>>>(qb, kfb, vfb, pob, zzb);

    gemm_out<<<dim3(NSP / 64, CDIM / 64, BATCH), 256, 0, stream>>>(
        wo_b, pob, zzb, bout, x, sOut, out, sOut, NSP);
}

// Round 17
// 78.556 us; speedup vs baseline: 1.2484x; 1.0456x over previous
//
#include <hip/hip_runtime.h>
#include <hip/hip_bf16.h>
#include <stdint.h>

typedef unsigned short u16;
typedef float f32x4 __attribute__((ext_vector_type(4)));
typedef float f32x16 __attribute__((ext_vector_type(16)));
typedef short bf16x8 __attribute__((ext_vector_type(8)));

#define NSP 4096      // H*W
#define CDIM 256
#define HID 256
#define NH 8
#define DH 32
#define NG 32
#define CPG 8
#define BATCH 2
#define SPLIT 2       // kv-split (flash-decoding)
#define GN_EPS 1e-5f
// K side carries SCALE^2 * log2(e)  (exp2-domain softmax)
#define QK2_SCALE 0.25503488f

#define MFMA32(A, B, C) __builtin_amdgcn_mfma_f32_32x32x16_bf16(A, B, C, 0, 0, 0)
#define MFMA16(A, B, C) __builtin_amdgcn_mfma_f32_16x16x32_bf16(A, B, C, 0, 0, 0)

__device__ __forceinline__ float bf2f(u16 u) {
    union { uint32_t i; float f; } v; v.i = ((uint32_t)u) << 16; return v.f;
}
__device__ __forceinline__ u16 f2bf(float f) {
    union { float f; uint32_t i; } v; v.f = f;
    uint32_t b = v.i;
    return (u16)((b + 0x7FFFu + ((b >> 16) & 1u)) >> 16);
}

// async global->LDS, 16B per lane; lds must be the wave-uniform base
__device__ __forceinline__ void gload16(const u16* g, u16* lds) {
    __builtin_amdgcn_global_load_lds(
        (const __attribute__((address_space(1))) uint32_t*)g,
        (__attribute__((address_space(3))) uint32_t*)lds, 16, 0, 0);
}

// swap lanes 32-63 of a with lanes 0-31 of b (both updated)
__device__ __forceinline__ void pl32swap(uint32_t& a, uint32_t& b) {
    asm("v_permlane32_swap_b32 %0, %1" : "+v"(a), "+v"(b));
}

// ---------------- GN partial stats (512 blocks) + distributed weight cvt ----------------
__global__ __launch_bounds__(256) void stats_partial(
    const float* __restrict__ x, float* __restrict__ partials,
    const float* __restrict__ wq, const float* __restrict__ wk,
    const float* __restrict__ wv, const float* __restrict__ wout,
    u16* __restrict__ wcat) {
    int blk = blockIdx.x;   // 512 blocks
    int t = threadIdx.x;
#pragma unroll
    for (int i = 0; i < 2; i++) {
        int idx = blk * 512 + i * 256 + t;
        const float* src = (idx < 65536) ? wq : (idx < 131072) ? wk : (idx < 196608) ? wv : wout;
        wcat[idx] = f2bf(src[idx & 65535]);
    }
    int bg = blk >> 3, sl = blk & 7;
    const float4* base = (const float4*)(x + (size_t)bg * (CPG * NSP) + sl * 4096);
    float s = 0.f, ss = 0.f;
#pragma unroll
    for (int i = 0; i < 4; i++) {
        float4 v = base[t + i * 256];
        s  += v.x + v.y + v.z + v.w;
        ss += v.x * v.x + v.y * v.y + v.z * v.z + v.w * v.w;
    }
    for (int m = 1; m < 64; m <<= 1) { s += __shfl_xor(s, m, 64); ss += __shfl_xor(ss, m, 64); }
    __shared__ float ls[4], lss[4];
    int w = t >> 6;
    if ((t & 63) == 0) { ls[w] = s; lss[w] = ss; }
    __syncthreads();
    if (t == 0) {
        partials[bg * 16 + sl * 2]     = ls[0] + ls[1] + ls[2] + ls[3];
        partials[bg * 16 + sl * 2 + 1] = lss[0] + lss[1] + lss[2] + lss[3];
    }
}

// ---------------- GN apply + transpose to (b, n, c) bf16 (finalizes stats inline) ----------------
__global__ void gn_apply(const float* __restrict__ x, const float* __restrict__ partials,
                         const float* __restrict__ gamma, const float* __restrict__ beta,
                         u16* __restrict__ xn) {
    __shared__ u16 tile[64][72];
    __shared__ float mr[8][2];
    int n0 = blockIdx.x * 64, c0 = blockIdx.y * 64, b = blockIdx.z;
    int t = threadIdx.x;
    if (t < 8) {
        int bg = b * NG + (c0 >> 3) + t;
        float s = 0.f, ss = 0.f;
#pragma unroll
        for (int sl = 0; sl < 8; sl++) {
            s  += partials[bg * 16 + sl * 2];
            ss += partials[bg * 16 + sl * 2 + 1];
        }
        float mean = s * (1.0f / 32768.0f);
        float var = ss * (1.0f / 32768.0f) - mean * mean;
        mr[t][0] = mean;
        mr[t][1] = rsqrtf(var + GN_EPS);
    }
    __syncthreads();
    int nl = t & 63, cq = t >> 6;
#pragma unroll
    for (int i = 0; i < 16; i++) {
        int cl = i * 4 + cq;
        int c = c0 + cl;
        float mean = mr[cl >> 3][0];
        float rstd = mr[cl >> 3][1];
        float v = x[((size_t)b * CDIM + c) * NSP + n0 + nl];
        v = (v - mean) * rstd * gamma[c] + beta[c];
        tile[cl][nl] = f2bf(v);
    }
    __syncthreads();
    int nr = t >> 2, cc = (t & 3) * 16;
    uint4 o0, o1;
    u16* p0 = (u16*)&o0; u16* p1 = (u16*)&o1;
#pragma unroll
    for (int j = 0; j < 8; j++) { p0[j] = tile[cc + j][nr]; p1[j] = tile[cc + 8 + j][nr]; }
    size_t orow = ((size_t)b * NSP + n0 + nr) * CDIM + c0 + cc;
    *(uint4*)(xn + orow) = o0;
    *(uint4*)(xn + orow + 8) = o1;
}

// ---------------- fused q/k/v projection, 128x128 tile, vectorized LDS-transposed epilogue ----------------
__global__ __launch_bounds__(256) void gemm_qkv(
    const u16* __restrict__ A, const u16* __restrict__ wcat,
    const float* __restrict__ bq, const float* __restrict__ bk, const float* __restrict__ bv,
    u16* __restrict__ qb, u16* __restrict__ kfb, u16* __restrict__ vfb) {
    __shared__ u16 SMEM[128 * 136];   // 34.8KB: staging (As|Bs 32KB) then epilogue tile
    u16* As = SMEM;
    u16* Bs = SMEM + 8192;
    int bz = blockIdx.z;
    const u16* Ab = A + (size_t)bz * NSP * CDIM;
    int n0 = blockIdx.x * 128, m0 = blockIdx.y * 128;
    int seg = n0 >> 8;                 // 0=q 1=k 2=v
    int t = threadIdx.x, lane = t & 63, w = t >> 6;
    int wr = w >> 1, wc = w & 1;
    f32x4 acc[4][4] = {};

    int srow = w * 8 + (lane >> 3);
    int scol = (lane & 7) * 8;
    const u16* asrc = Ab + (size_t)(m0 + srow) * CDIM + scol;
    const u16* bsrc = wcat + (size_t)(n0 + srow) * CDIM + scol;
    u16* albase = As + w * 512;
    u16* blbase = Bs + w * 512;

    int frow = lane & 15, fcol = (lane >> 4) * 8;

    for (int k0 = 0; k0 < CDIM; k0 += 64) {
        __syncthreads();
#pragma unroll
        for (int ro = 0; ro < 4; ro++) {
            gload16(asrc + (size_t)ro * 32 * CDIM + k0, albase + ro * 2048);
            gload16(bsrc + (size_t)ro * 32 * CDIM + k0, blbase + ro * 2048);
        }
        asm volatile("s_waitcnt vmcnt(0)" ::: "memory");
        __syncthreads();
#pragma unroll
        for (int kk = 0; kk < 2; kk++) {
            bf16x8 af[4], bfv[4];
#pragma unroll
            for (int i = 0; i < 4; i++) {
                af[i]  = *(bf16x8*)&As[(wr * 64 + i * 16 + frow) * 64 + kk * 32 + fcol];
                bfv[i] = *(bf16x8*)&Bs[(wc * 64 + i * 16 + frow) * 64 + kk * 32 + fcol];
            }
#pragma unroll
            for (int i = 0; i < 4; i++)
#pragma unroll
                for (int j = 0; j < 4; j++)
                    acc[i][j] = MFMA16(af[i], bfv[j], acc[i][j]);
        }
    }

    const float* bias = (seg == 0) ? bq : (seg == 1) ? bk : bv;
    int r4 = (lane >> 4) * 4, cx = lane & 15;
    const int STR = 136;
    __syncthreads();   // all waves done reading As/Bs before SMEM reuse

    if (seg <= 1) {
#pragma unroll
        for (int i = 0; i < 4; i++) {
            int row_l = wr * 64 + i * 16 + r4;
#pragma unroll
            for (int j = 0; j < 4; j++) {
                int col_l = wc * 64 + j * 16 + cx;
                float bb = bias[(n0 & 255) + col_l];
#pragma unroll
                for (int r = 0; r < 4; r++) {
                    float vv = acc[i][j][r] + bb;
                    if (seg == 1) vv *= QK2_SCALE;
                    SMEM[(row_l + r) * STR + col_l] = f2bf(vv);
                }
            }
        }
        __syncthreads();
        if (seg == 0) {
#pragma unroll
            for (int i = 0; i < 8; i++) {
                int c = i * 256 + t;
                int row = c >> 4, o = c & 15;
                uint4 v = *(uint4*)&SMEM[row * STR + o * 8];
                *(uint4*)(qb + (size_t)bz * NSP * HID + (size_t)(m0 + row) * HID + (n0 & 255) + o * 8) = v;
            }
        } else {
#pragma unroll
            for (int i = 0; i < 8; i++) {
                int c = i * 256 + t;
                int rl = c & 127, o = c >> 7;
                int colg = (n0 & 255) + o * 8;
                int h2 = colg >> 5;
                int rg = m0 + rl;
                int f = 2 * ((rg >> 5) & 1) + ((colg >> 4) & 1);
                size_t off = ((size_t)(bz * NH + h2) * 64 + (rg >> 6)) * 2048 + (size_t)f * 512
                           + (size_t)(rg & 31) * 8 + (size_t)((colg >> 3) & 1) * 256;
                *(uint4*)(kfb + off) = *(uint4*)&SMEM[rl * STR + o * 8];
            }
        }
    } else {
#pragma unroll
        for (int i = 0; i < 4; i++) {
            int row_l = wr * 64 + i * 16 + r4;
#pragma unroll
            for (int j = 0; j < 4; j++) {
                int col_l = wc * 64 + j * 16 + cx;
                float bb = bias[(n0 & 255) + col_l];
                uint2 pk2;
                pk2.x = ((uint32_t)f2bf(acc[i][j][1] + bb) << 16) | f2bf(acc[i][j][0] + bb);
                pk2.y = ((uint32_t)f2bf(acc[i][j][3] + bb) << 16) | f2bf(acc[i][j][2] + bb);
                *(uint2*)&SMEM[col_l * STR + row_l] = pk2;
            }
        }
        __syncthreads();
#pragma unroll
        for (int i = 0; i < 8; i++) {
            int c = i * 256 + t;
            int dl = c & 127, jl = c >> 7;
            int colg = (n0 & 255) + dl;
            int h2 = colg >> 5, d = colg & 31;
            int ng = m0 + jl * 8;
            int jc = (ng >> 3) & 7;
            size_t off = ((size_t)(bz * NH + h2) * 64 + (ng >> 6)) * 2048 + (size_t)(jc >> 1) * 512
                       + (size_t)(d + (jc & 1) * 32) * 8;
            *(uint4*)(vfb + off) = *(uint4*)&SMEM[dl * STR + jl * 8];
        }
    }
}

// ---------------- final GEMM + fused split-combine (SPLIT=2) ----------------
__global__ __launch_bounds__(256) void gemm_out(
    const u16* __restrict__ A,           // wout bf16 (256x256)
    const u16* __restrict__ po, const float* __restrict__ zz,
    const float* __restrict__ bias,
    const float* __restrict__ resid, long sR,
    float* __restrict__ outp, long sO,
    int N) {
    __shared__ u16 As[64][72];
    __shared__ u16 Bs[64][72];
    int bz = blockIdx.z;
    int m0 = blockIdx.y * 64, n0 = blockIdx.x * 64;
    int t = threadIdx.x, lane = t & 63, w = t >> 6;
    int wm = (w >> 1) * 32, wn = (w & 1) * 32;
    f32x4 acc[2][2] = {};

    int sr = t >> 2;
    int sc1 = (t & 3) * 8, sc2 = sc1 + 32;
    int nrow = n0 + sr;
    const size_t SSTRIDE = (size_t)NH * NSP;   // split stride in zz rows

    // combined B value for channels [c, c+8) of spatial row nrow
    auto cmb = [&](int c) -> uint4 {
        int h = c >> 5, d = c & 31;
        size_t zb = (((size_t)(bz * SPLIT) * NH + h) * NSP) + nrow;
        float z0 = zz[zb];
        float z1 = zz[zb + SSTRIDE];
        float M = fmaxf(z0, z1);
        float w0 = __builtin_amdgcn_exp2f(z0 - M);
        float w1 = __builtin_amdgcn_exp2f(z1 - M);
        float inv = 1.0f / (w0 + w1);
        w0 *= inv; w1 *= inv;
        uint4 o0 = *(const uint4*)(po + zb * DH + d);
        uint4 o1 = *(const uint4*)(po + (zb + SSTRIDE) * DH + d);
        const u16* p0 = (const u16*)&o0;
        const u16* p1 = (const u16*)&o1;
        uint4 r;
        u16* rp = (u16*)&r;
#pragma unroll
        for (int j = 0; j < 8; j++) {
            float a = bf2f(p0[j]) * w0 + bf2f(p1[j]) * w1;
            rp[j] = f2bf(a);
        }
        return r;
    };

    uint4 av0 = *(const uint4*)(A + (size_t)(m0 + sr) * CDIM + sc1);
    uint4 av1 = *(const uint4*)(A + (size_t)(m0 + sr) * CDIM + sc2);

    for (int k0 = 0; k0 < CDIM; k0 += 64) {
        uint4 bv0 = cmb(k0 + sc1);
        uint4 bv1 = cmb(k0 + sc2);
        __syncthreads();
        *(uint4*)&As[sr][sc1] = av0;
        *(uint4*)&As[sr][sc2] = av1;
        *(uint4*)&Bs[sr][sc1] = bv0;
        *(uint4*)&Bs[sr][sc2] = bv1;
        __syncthreads();
        if (k0 + 64 < CDIM) {
            av0 = *(const uint4*)(A + (size_t)(m0 + sr) * CDIM + k0 + 64 + sc1);
            av1 = *(const uint4*)(A + (size_t)(m0 + sr) * CDIM + k0 + 64 + sc2);
        }
#pragma unroll
        for (int ks = 0; ks < 2; ks++) {
            bf16x8 af[2], bfr[2];
#pragma unroll
            for (int i = 0; i < 2; i++) {
                af[i]  = *(bf16x8*)&As[wm + i * 16 + (lane & 15)][ks * 32 + (lane >> 4) * 8];
                bfr[i] = *(bf16x8*)&Bs[wn + i * 16 + (lane & 15)][ks * 32 + (lane >> 4) * 8];
            }
#pragma unroll
            for (int i = 0; i < 2; i++)
#pragma unroll
                for (int j = 0; j < 2; j++)
                    acc[i][j] = MFMA16(af[i], bfr[j], acc[i][j]);
        }
    }

    int r4 = (lane >> 4) * 4, cx = lane & 15;
#pragma unroll
    for (int i = 0; i < 2; i++)
#pragma unroll
        for (int j = 0; j < 2; j++) {
            int rbase = m0 + wm + i * 16 + r4;
            int cbase = n0 + wn + j * 16 + cx;
#pragma unroll
            for (int r = 0; r < 4; r++) {
                int row = rbase + r, col = cbase;
                outp[(size_t)bz * sO + (size_t)row * N + col] =
                    acc[i][j][r] + bias[row] + resid[(size_t)bz * sR + (size_t)row * N + col];
            }
        }
}

// ---------------- flash attention: barrier-free, LDS-free, DUAL q-stream, 2-tile prefetch ----------------
__global__ __launch_bounds__(256, 3) void attn_kernel(
    const u16* __restrict__ q, const u16* __restrict__ kfb,
    const u16* __restrict__ vfb, u16* __restrict__ po, float* __restrict__ zz) {
    __shared__ float Ls[4][64];
    int h = blockIdx.y;
    int bz = blockIdx.z;
    int b = bz / SPLIT, sp = bz % SPLIT;
    int kv0 = sp * (NSP / SPLIT);
    int t = threadIdx.x, lane = t & 63, w = t >> 6;
    int ql = lane & 31, hi = lane >> 5;
    int q0 = blockIdx.x * 256 + w * 64;   // stream a: q0..q0+31, stream b: q0+32..q0+63

    const u16* qbp = q + (size_t)b * NSP * HID + (size_t)(q0 + ql) * HID + h * DH + hi * 8;
    bf16x8 qa0 = *(const bf16x8*)(qbp);
    bf16x8 qa1 = *(const bf16x8*)(qbp + 16);
    bf16x8 qb0 = *(const bf16x8*)(qbp + 32 * HID);
    bf16x8 qb1 = *(const bf16x8*)(qbp + 32 * HID + 16);

    size_t tbase = ((size_t)(b * NH + h) * 64 + (kv0 >> 6)) * 2048 + (size_t)lane * 8;
    const u16* kp = kfb + tbase;
    const u16* vp = vfb + tbase;

#define LOADKF(kd, it) { \
    kd[0] = *(const bf16x8*)(kp + (size_t)(it) * 2048);        \
    kd[1] = *(const bf16x8*)(kp + (size_t)(it) * 2048 + 512);  \
    kd[2] = *(const bf16x8*)(kp + (size_t)(it) * 2048 + 1024); \
    kd[3] = *(const bf16x8*)(kp + (size_t)(it) * 2048 + 1536); }
#define LOADVF(vd, it) { \
    vd[0] = *(const bf16x8*)(vp + (size_t)(it) * 2048);        \
    vd[1] = *(const bf16x8*)(vp + (size_t)(it) * 2048 + 512);  \
    vd[2] = *(const bf16x8*)(vp + (size_t)(it) * 2048 + 1024); \
    vd[3] = *(const bf16x8*)(vp + (size_t)(it) * 2048 + 1536); }

    f32x16 kzero = {};
    f32x16 oacc_a = {}, oacc_b = {};
    float la0 = 0.f, la1 = 0.f, lb0 = 0.f, lb1 = 0.f;

    auto softpv = [&](f32x16& st, const bf16x8 (&vf)[4], int tt, f32x16& oacc,
                      float& l0, float& l1) {
        uint32_t pk[8];
#pragma unroll
        for (int j = 0; j < 8; j++) {
            float p0 = __builtin_amdgcn_exp2f(st[2 * j]);
            float p1 = __builtin_amdgcn_exp2f(st[2 * j + 1]);
            float ps = p0 + p1;
            if (j & 1) l1 += ps; else l0 += ps;
            uint32_t dd;
            asm("v_cvt_pk_bf16_f32 %0, %1, %2" : "=v"(dd) : "v"(p0), "v"(p1));
            pk[j] = dd;
        }
#pragma unroll
        for (int c = 0; c < 2; c++) {
            uint32_t a0 = pk[4 * c + 0], b0 = pk[4 * c + 2];
            uint32_t a1 = pk[4 * c + 1], b1 = pk[4 * c + 3];
            pl32swap(a0, b0);
            pl32swap(a1, b1);
            union { uint32_t u[4]; bf16x8 v8; } fr;
            fr.u[0] = a0; fr.u[1] = a1; fr.u[2] = b0; fr.u[3] = b1;
            __builtin_amdgcn_s_setprio(1);
            oacc = MFMA32(fr.v8, vf[2 * tt + c], oacc);
            __builtin_amdgcn_s_setprio(0);
        }
    };

    auto process = [&](const bf16x8 (&kf)[4], const bf16x8 (&vf)[4]) {
#pragma unroll
        for (int tt = 0; tt < 2; tt++) {
            __builtin_amdgcn_s_setprio(1);
            f32x16 st_a = MFMA32(kf[2 * tt], qa0, kzero);
            st_a = MFMA32(kf[2 * tt + 1], qa1, st_a);
            f32x16 st_b = MFMA32(kf[2 * tt], qb0, kzero);
            st_b = MFMA32(kf[2 * tt + 1], qb1, st_b);
            __builtin_amdgcn_s_setprio(0);
            softpv(st_a, vf, tt, oacc_a, la0, la1);
            softpv(st_b, vf, tt, oacc_b, lb0, lb1);
        }
    };

    const int NT = (NSP / SPLIT) / 64;   // 32 tiles (even)
    bf16x8 k0[4], v0[4], k1[4], v1[4];
    LOADKF(k0, 0); LOADVF(v0, 0);
    LOADKF(k1, 1); LOADVF(v1, 1);
    for (int it = 0; it < NT; it += 2) {
        process(k0, v0);
        int n2 = (it + 2 < NT) ? it + 2 : 0;
        LOADKF(k0, n2); LOADVF(v0, n2);
        process(k1, v1);
        int n3 = (it + 3 < NT) ? it + 3 : 0;
        LOADKF(k1, n3); LOADVF(v1, n3);
    }
#undef LOADKF
#undef LOADVF

    float la = la0 + la1;
    float lb = lb0 + lb1;
    la += __shfl_xor(la, 32);
    lb += __shfl_xor(lb, 32);
    Ls[w][ql] = 1.0f / la;
    Ls[w][32 + ql] = 1.0f / lb;
    if (hi == 0) {
        zz[(((size_t)bz * NH + h) * NSP) + q0 + ql] = __log2f(la);
        zz[(((size_t)bz * NH + h) * NSP) + q0 + 32 + ql] = __log2f(lb);
    }
    u16* pob = po + ((((size_t)bz * NH + h) * NSP) + q0) * DH + ql;
#pragma unroll
    for (int r = 0; r < 16; r++) {
        int qq = (r & 3) + 8 * (r >> 2) + 4 * hi;
        pob[(size_t)qq * DH] = f2bf(oacc_a[r] * Ls[w][qq]);
        pob[(size_t)(32 + qq) * DH] = f2bf(oacc_b[r] * Ls[w][32 + qq]);
    }
}

extern "C" void kernel_launch(void* const* d_in, const int* in_sizes, int n_in,
                              void* d_out, int out_size, void* d_ws, size_t ws_size,
                              hipStream_t stream) {
    const float* x     = (const float*)d_in[0];
    const float* gamma = (const float*)d_in[1];
    const float* beta  = (const float*)d_in[2];
    const float* wq    = (const float*)d_in[3];
    const float* bq    = (const float*)d_in[4];
    const float* wk    = (const float*)d_in[5];
    const float* bk    = (const float*)d_in[6];
    const float* wv    = (const float*)d_in[7];
    const float* bv    = (const float*)d_in[8];
    const float* wout  = (const float*)d_in[9];
    const float* bout  = (const float*)d_in[10];
    float* out = (float*)d_out;

    char* ws = (char*)d_ws;
    float* partials = (float*)ws;                    // 64*8*2 floats = 4KB
    u16* wq_b = (u16*)(ws + 4096);                   // wq|wk|wv|wout contiguous
    u16* wo_b = wq_b + 3 * 65536;
    u16* xn = wo_b + 65536;                          // (b,n,c) bf16, 4 MB
    u16* qb = xn + (size_t)BATCH * NSP * CDIM;       // (b,n,hid) 4 MB
    u16* kfb = qb + (size_t)BATCH * NSP * HID;       // frag K 4 MB
    u16* vfb = kfb + (size_t)BATCH * NH * 64 * 2048; // frag V 4 MB
    u16* pob = vfb + (size_t)BATCH * NH * 64 * 2048; // (b,sp,h,n,d) 8 MB
    float* zzb = (float*)(pob + (size_t)SPLIT * BATCH * NH * NSP * DH);  // 0.5 MB

    const long sOut = (long)CDIM * NSP;

    stats_partial<<<512, 256, 0, stream>>>(x, partials, wq, wk, wv, wout, wq_b);
    gn_apply<<<dim3(NSP / 64, CDIM / 64, BATCH), 256, 0, stream>>>(x, partials, gamma, beta, xn);

    gemm_qkv<<<dim3(768 / 128, NSP / 128, BATCH), 256, 0, stream>>>(
        xn, wq_b, bq, bk, bv, qb, kfb, vfb);

    attn_kernel<<<dim3(NSP / 256, NH, BATCH * SPLIT), 256, 0, stream>>>(qb, kfb, vfb, pob, zzb);

    gemm_out<<<dim3(NSP / 64, CDIM / 64, BATCH), 256, 0, stream>>>(
        wo_b, pob, zzb, bout, x, sOut, out, sOut, NSP);
}